// Round 7
// baseline (414.301 us; speedup 1.0000x reference)
//
#include <hip/hip_runtime.h>
#include <hip/hip_bf16.h>
#include <math.h>

#define B_ 64
#define S_ 512
#define VEC_ 768
#define H_ 256
#define M_ (B_*S_)   // 32768

typedef float floatx4 __attribute__((ext_vector_type(4)));
typedef __bf16 bf16x8 __attribute__((ext_vector_type(8)));
typedef __bf16 bf16x4 __attribute__((ext_vector_type(4)));

// prep: cast mlp_w -> bf16; zero doc-sum accumulators; transpose fd_w -> fd_wT
__global__ __launch_bounds__(256) void prep_kernel(
    const float* __restrict__ mlp_w, const float* __restrict__ fd_w,
    __bf16* __restrict__ wbf, float* __restrict__ sums, float* __restrict__ fd_wT)
{
  const int bid = blockIdx.x;
  const int t = threadIdx.x;
  if (bid < 192) {
    const int i = bid * 256 + t;                     // float4 index, 49152 total
    const float4 v = ((const float4*)mlp_w)[i];
    bf16x4 b = { (__bf16)v.x, (__bf16)v.y, (__bf16)v.z, (__bf16)v.w };
    *(bf16x4*)&wbf[(size_t)i * 4] = b;
  } else if (bid < 224) {
    const int i = (bid - 192) * 256 + t;             // 8192 float4 = 2*64*256 f32
    ((float4*)sums)[i] = make_float4(0.f, 0.f, 0.f, 0.f);
  } else {
    // transpose fd_w [256][512] -> fd_wT [512][256]; 64 blocks x 4 rows
    const int j0 = (bid - 224) * 4;
#pragma unroll
    for (int rr = 0; rr < 4; ++rr) {
      const int j = j0 + rr;
      for (int k = t; k < 512; k += 256)
        fd_wT[(size_t)k * 256 + j] = fd_w[(size_t)j * 512 + k];
    }
  }
}

// ---------------- GEMM: 32x128 wave tiles (LDS-pressure cut) ----------------
// r0-r6 falsified: schedule, page-locality, barriers, occupancy. Unchanged
// invariant was the wave tile (16x256): every wave read the WHOLE B tile from
// LDS each K-step (16 ds_read : 16 MFMA, 16x redundancy, ~6MB LDS/CU). Now
// 16 waves = 8m x 2n, tile 32x128: 8 ds_read + 4 A-gloads + 16 MFMA per step;
// LDS traffic/redundancy halved, A-prefetch depth 3, A never in LDS, barriers
// lgkm-only every 4 K-steps (B-chunk of 128, double-buffered 2x64KB).
#define CHUNKB_ 65536

__device__ __forceinline__ bf16x8 cvt8(float4 a, float4 b) {
  bf16x8 v;
  v[0] = (__bf16)a.x; v[1] = (__bf16)a.y; v[2] = (__bf16)a.z; v[3] = (__bf16)a.w;
  v[4] = (__bf16)b.x; v[5] = (__bf16)b.y; v[6] = (__bf16)b.z; v[7] = (__bf16)b.w;
  return v;
}

__global__ __launch_bounds__(1024, 4) void gemm_doc_kernel(
    const float* __restrict__ out1, const float* __restrict__ out2,
    const __bf16* __restrict__ wbf, const float* __restrict__ mlp_b,
    __bf16* __restrict__ o1, float* __restrict__ sum1, float* __restrict__ sum2)
{
  __shared__ __align__(16) char smem[2 * CHUNKB_];

  const int tensor = blockIdx.y;
  const float* __restrict__ A = tensor ? out2 : out1;
  float* __restrict__ dsum = tensor ? sum2 : sum1;

  const int m0 = blockIdx.x * 256;          // 256 rows per block
  const int bidx = blockIdx.x >> 1;         // doc = 512 rows = 2 blocks
  const int t = threadIdx.x;
  const int lane = t & 63;
  const int wave = t >> 6;                  // 16 waves: 8 m-groups x 2 n-groups
  const int q = lane >> 4;
  const int c = lane & 15;
  const int wm = (wave >> 1) * 32;          // 32-row strip
  const int wnb = (wave & 1) * 32768;       // n-half byte offset in B LDS (128 cols)

  // A fragment source: rows m0+wm+c (i=0) and +16 (i=1), k-slot base q*8
  const float* Ap = A + (size_t)(m0 + wm + c) * VEC_ + q * 8;

  // B staging: thread t owns LDS row t>>2 (n), quarter t&3 (4 x 16B slots)
  const int brow = t >> 2, bq = t & 3;
  const __bf16* Bsrc = wbf + (size_t)brow * VEC_ + bq * 32;
  char* Bdst = smem + brow * 256;

  floatx4 acc[16];   // [i*8+j]: i in {0,1} row-block, j in 0..7 col-frag
#pragma unroll
  for (int j = 0; j < 16; j++) acc[j] = (floatx4){0.f, 0.f, 0.f, 0.f};

  float4 aR[3][4];   // depth-3 rotation x (2 frags x 2 halves), literal idx
  bf16x8 sR[4];      // B-stage regs

#define ALOAD(st) {                                                           \
    aR[(st) % 3][0] = *(const float4*)(Ap + (st) * 32);                       \
    aR[(st) % 3][1] = *(const float4*)(Ap + (st) * 32 + 4);                   \
    aR[(st) % 3][2] = *(const float4*)(Ap + 16 * VEC_ + (st) * 32);           \
    aR[(st) % 3][3] = *(const float4*)(Ap + 16 * VEC_ + (st) * 32 + 4); }

#define BLOAD(kc) { _Pragma("unroll")                                         \
    for (int i_ = 0; i_ < 4; i_++)                                            \
      sR[i_] = *(const bf16x8*)(Bsrc + (kc) * 128 + i_ * 8); }

#define BWRITE(kc) { _Pragma("unroll")                                        \
    for (int i_ = 0; i_ < 4; i_++)                                            \
      *(bf16x8*)(Bdst + ((kc) & 1) * CHUNKB_ +                                \
                 (((bq * 4 + i_) ^ (brow & 7)) * 16)) = sR[i_]; }

  // K-step of 32: cvt A(st), refill A(st+3), 8 swizzled ds_read, 16 MFMA
#define KSTEP(st) {                                                           \
    const bf16x8 af0 = cvt8(aR[(st) % 3][0], aR[(st) % 3][1]);                \
    const bf16x8 af1 = cvt8(aR[(st) % 3][2], aR[(st) % 3][3]);                \
    if ((st) + 3 < 24) ALOAD((st) + 3)                                        \
    const char* bb = smem + (((st) >> 2) & 1) * CHUNKB_ + wnb + c * 256 +     \
                     (((((st) & 3) * 4 + q) ^ (c & 7)) * 16);                 \
    bf16x8 bfr[8];                                                            \
    _Pragma("unroll")                                                         \
    for (int j = 0; j < 8; j++) bfr[j] = *(const bf16x8*)(bb + j * 4096);     \
    _Pragma("unroll")                                                         \
    for (int j = 0; j < 8; j++)                                               \
      acc[j] = __builtin_amdgcn_mfma_f32_16x16x32_bf16(af0, bfr[j], acc[j], 0, 0, 0); \
    _Pragma("unroll")                                                         \
    for (int j = 0; j < 8; j++)                                               \
      acc[8 + j] = __builtin_amdgcn_mfma_f32_16x16x32_bf16(af1, bfr[j], acc[8 + j], 0, 0, 0); \
  }

  // chunk boundary: publish next B chunk, refill stage regs, raw barrier.
  // lgkmcnt-only (NO vmcnt drain): A-loads stay in flight across barriers.
#define BOUNDARY(cn) {                                                        \
    BWRITE((cn) + 1)                                                          \
    if ((cn) < 4) BLOAD((cn) + 2)                                             \
    asm volatile("s_waitcnt lgkmcnt(0)" ::: "memory");                        \
    __builtin_amdgcn_s_barrier(); }

  // prologue
  ALOAD(0) ALOAD(1) ALOAD(2)
  BLOAD(0)
  BWRITE(0)
  BLOAD(1)
  asm volatile("s_waitcnt lgkmcnt(0)" ::: "memory");
  __builtin_amdgcn_s_barrier();

  KSTEP(0)  KSTEP(1)  KSTEP(2)  KSTEP(3)  BOUNDARY(0)
  KSTEP(4)  KSTEP(5)  KSTEP(6)  KSTEP(7)  BOUNDARY(1)
  KSTEP(8)  KSTEP(9)  KSTEP(10) KSTEP(11) BOUNDARY(2)
  KSTEP(12) KSTEP(13) KSTEP(14) KSTEP(15) BOUNDARY(3)
  KSTEP(16) KSTEP(17) KSTEP(18) KSTEP(19) BOUNDARY(4)
  KSTEP(20) KSTEP(21) KSTEP(22) KSTEP(23)

#undef ALOAD
#undef BLOAD
#undef BWRITE
#undef KSTEP
#undef BOUNDARY

  // epilogue: bias + relu, store bf16 (tensor 0), column sums -> atomicAdd
#pragma unroll
  for (int j = 0; j < 8; j++) {
    const int n = (wave & 1) * 128 + j * 16 + c;
    const float bias = mlp_b[n];
    float colsum = 0.f;
#pragma unroll
    for (int i = 0; i < 2; i++) {
      const int mb = m0 + wm + i * 16 + q * 4;
#pragma unroll
      for (int r = 0; r < 4; r++) {
        float v = acc[i * 8 + j][r] + bias;
        v = fmaxf(v, 0.f);
        colsum += v;
        if (tensor == 0) o1[(size_t)(mb + r) * H_ + n] = (__bf16)v;
      }
    }
    colsum += __shfl_down(colsum, 32);
    colsum += __shfl_down(colsum, 16);
    if (lane < 16)
      atomicAdd(&dsum[bidx * H_ + (wave & 1) * 128 + j * 16 + lane], colsum);
  }
}

// logits: grid (8, B): block handles 64 s-rows (16 per wave); block 0/wave 0
// also does row 512. lg[b,s] = dot(o1_row or o1_doc, o2_doc)
__global__ __launch_bounds__(256) void logits_kernel(
    const __bf16* __restrict__ o1, const float* __restrict__ sum1,
    const float* __restrict__ sum2, float* __restrict__ lg)
{
  const int b = blockIdx.y;
  const int t = threadIdx.x, lane = t & 63, wave = t >> 6;
  const float sc = 1.f / 512.f;
  const float4 w4 = ((const float4*)&sum2[b * H_])[lane];
  const int sbase = blockIdx.x * 64 + wave * 16;
#pragma unroll 4
  for (int u = 0; u < 16; ++u) {
    const int s = sbase + u;
    const bf16x4 x = ((const bf16x4*)&o1[((size_t)b * S_ + s) * H_])[lane];
    float p = ((float)x[0] * w4.x + (float)x[1] * w4.y +
               (float)x[2] * w4.z + (float)x[3] * w4.w) * sc;
    p += __shfl_down(p, 32); p += __shfl_down(p, 16); p += __shfl_down(p, 8);
    p += __shfl_down(p, 4);  p += __shfl_down(p, 2);  p += __shfl_down(p, 1);
    if (lane == 0) lg[b * 513 + s] = p;
  }
  if (blockIdx.x == 0 && wave == 0) {
    const float4 x = ((const float4*)&sum1[b * H_])[lane];
    float p = (x.x * w4.x + x.y * w4.y + x.z * w4.z + x.w * w4.w) * sc * sc;
    p += __shfl_down(p, 32); p += __shfl_down(p, 16); p += __shfl_down(p, 8);
    p += __shfl_down(p, 4);  p += __shfl_down(p, 2);  p += __shfl_down(p, 1);
    if (lane == 0) lg[b * 513 + 512] = p;
  }
}

// fused: MLP head (row 512 of att) + softmax over 513 logits (rows 0..511)
// fd_wT is the pre-transposed [512][256] weight -> lane-coalesced dot.
__global__ __launch_bounds__(256) void softmax_head_kernel(
    const float* __restrict__ lg, const float* __restrict__ sum1, const float* __restrict__ sum2,
    const float* __restrict__ fd_wT, const float* __restrict__ fd_b,
    const float* __restrict__ ff_w, const float* __restrict__ ff_b,
    float* __restrict__ out)
{
  const int b = blockIdx.x, t = threadIdx.x, lane = t & 63, wave = t >> 6;
  __shared__ __align__(16) float dc[512];
  __shared__ float sl[513];
  __shared__ float red[4], r1[4], r2[4];

  dc[t]       = sum1[b * H_ + t] * (1.f / 512.f);
  dc[t + 256] = sum2[b * H_ + t] * (1.f / 512.f);
  for (int i = t; i < 513; i += 256) sl[i] = lg[b * 513 + i];
  __syncthreads();
  // h[t] = relu(sum_k fd_wT[k][t] * dc[k] + fd_b[t]) — coalesced over t
  float a0 = 0.f, a1 = 0.f, a2 = 0.f, a3 = 0.f;
#pragma unroll 4
  for (int k = 0; k < 512; k += 4) {
    a0 += fd_wT[(size_t)(k + 0) * 256 + t] * dc[k + 0];
    a1 += fd_wT[(size_t)(k + 1) * 256 + t] * dc[k + 1];
    a2 += fd_wT[(size_t)(k + 2) * 256 + t] * dc[k + 2];
    a3 += fd_wT[(size_t)(k + 3) * 256 + t] * dc[k + 3];
  }
  const float h = fmaxf((a0 + a1) + (a2 + a3) + fd_b[t], 0.f);
  float part = ff_w[t] * h;
  part += __shfl_down(part, 32); part += __shfl_down(part, 16);
  part += __shfl_down(part, 8);  part += __shfl_down(part, 4);
  part += __shfl_down(part, 2);  part += __shfl_down(part, 1);
  if (lane == 0) red[wave] = part;

  // --- softmax over sl[0..512]
  float m = -1e30f;
  for (int i = t; i < 513; i += 256) m = fmaxf(m, sl[i]);
  m = fmaxf(m, __shfl_down(m, 32)); m = fmaxf(m, __shfl_down(m, 16));
  m = fmaxf(m, __shfl_down(m, 8));  m = fmaxf(m, __shfl_down(m, 4));
  m = fmaxf(m, __shfl_down(m, 2));  m = fmaxf(m, __shfl_down(m, 1));
  if (lane == 0) r1[wave] = m;
  __syncthreads();
  m = fmaxf(fmaxf(r1[0], r1[1]), fmaxf(r1[2], r1[3]));
  float psum = 0.f;
  for (int i = t; i < 513; i += 256) { const float e = expf(sl[i] - m); sl[i] = e; psum += e; }
  psum += __shfl_down(psum, 32); psum += __shfl_down(psum, 16); psum += __shfl_down(psum, 8);
  psum += __shfl_down(psum, 4);  psum += __shfl_down(psum, 2);  psum += __shfl_down(psum, 1);
  if (lane == 0) r2[wave] = psum;
  __syncthreads();
  const float inv = 1.f / (r2[0] + r2[1] + r2[2] + r2[3]);
  for (int s = t; s < 512; s += 256) out[s * 64 + b] = sl[s] * inv;
  if (t == 0) {
    const float tot = red[0] + red[1] + red[2] + red[3] + ff_b[0];
    out[(size_t)512 * 64 + b] = 1.f / (1.f + expf(-tot));
  }
}

extern "C" void kernel_launch(void* const* d_in, const int* in_sizes, int n_in,
                              void* d_out, int out_size, void* d_ws, size_t ws_size,
                              hipStream_t stream) {
  const float* out1  = (const float*)d_in[0];
  const float* out2  = (const float*)d_in[1];
  const float* mlp_w = (const float*)d_in[2];
  const float* mlp_b = (const float*)d_in[3];
  const float* fd_w  = (const float*)d_in[4];
  const float* fd_b  = (const float*)d_in[5];
  const float* ff_w  = (const float*)d_in[6];
  const float* ff_b  = (const float*)d_in[7];
  float* out = (float*)d_out;

  __bf16* o1  = (__bf16*)d_ws;                       // 32768*256 bf16 = 16.78 MB
  __bf16* wbf = o1 + (size_t)M_ * H_;                // 256*768 bf16
  float*  s1  = (float*)(wbf + (size_t)H_ * VEC_);   // 64*256 f32
  float*  s2  = s1 + B_ * H_;                        // 64*256 f32
  float*  lgw = s2 + B_ * H_;                        // 64*513 f32
  float*  fwt = lgw + B_ * 513;                      // 512*256 f32 = 512 KB

  prep_kernel<<<288, 256, 0, stream>>>(mlp_w, fd_w, wbf, s1, fwt);
  gemm_doc_kernel<<<dim3(128, 2), 1024, 0, stream>>>(out1, out2, wbf, mlp_b, o1, s1, s2);
  logits_kernel<<<dim3(8, B_), 256, 0, stream>>>(o1, s1, s2, lgw);
  softmax_head_kernel<<<B_, 256, 0, stream>>>(lgw, s1, s2, fwt, fd_b, ff_w, ff_b, out);
}